// Round 8
// baseline (114.860 us; speedup 1.0000x reference)
//
#include <hip/hip_runtime.h>
#include <hip/hip_bf16.h>
#include <stdint.h>

// out = softmax(x1, -1) @ x2
// x1: [1,16,2048,2048] fp32, x2: [1,16,2048,64] fp32, out: [1,16,2048,64] fp32
//
// R8 = R1 (64.4us, best so far) with ONE targeted change: the x1 stream and
// the output stores are NONTEMPORAL (no L2/L3 allocate). Theory (story A):
// R1 runs at BW ceiling but wastes ~128MB re-fetching V tiles from HBM
// because the 268MB x1 stream flushes L2 (4MiB/XCD turns over every ~5us)
// and L3 (256MiB ~ x1 size). NT x1 leaves V (4MB bf16 x2t) cache-resident,
// so per-iteration V re-stages hit L2/L3 instead of HBM.
// x1 staging reads are full 512B/wave contiguous segments -> NT cannot cause
// R4-style half-line waste. Everything else is byte-identical to R1.

#define H_  16
#define S_  2048
#define D_  64
#define KT  128   // K elements staged per iteration
#define QT  64    // output rows per block (16 per wave, 4 waves)
#define NT  (S_ / KT)  // 16

typedef short bf16x8 __attribute__((ext_vector_type(8)));  // 8 bf16 (4 VGPRs)
typedef float f32x4  __attribute__((ext_vector_type(4)));

__device__ __forceinline__ uint16_t f2bf(float f) {  // round-to-nearest-even
  uint32_t u = __builtin_bit_cast(uint32_t, f);
  u += 0x7fffu + ((u >> 16) & 1u);
  return (uint16_t)(u >> 16);
}

// Pre-kernel: x2 [H][S][D] fp32  ->  x2t [H][D][S] bf16 (k-contiguous rows)
// x2 reads NT (read-once); x2t writes regular (about to be re-read 128x).
__global__ __launch_bounds__(256) void vtrans_kernel(const float* __restrict__ x2,
                                                     uint16_t* __restrict__ x2t) {
  __shared__ float t[D_][64 + 1];  // +1 pad: bank-conflict-free transpose
  const int h  = blockIdx.x >> 5;
  const int k0 = (blockIdx.x & 31) << 6;  // 64-k tile
  const float* src = x2 + ((size_t)h * S_ + k0) * D_;
#pragma unroll
  for (int p = 0; p < 4; ++p) {
    int flat = p * 1024 + threadIdx.x * 4;
    int k = flat >> 6, d = flat & 63;
    f32x4 v = __builtin_nontemporal_load((const f32x4*)(src + (size_t)k * D_ + d));
    t[d + 0][k] = v[0]; t[d + 1][k] = v[1]; t[d + 2][k] = v[2]; t[d + 3][k] = v[3];
  }
  __syncthreads();
  uint16_t* dst = x2t + (size_t)h * D_ * S_ + k0;
#pragma unroll
  for (int p = 0; p < 4; ++p) {
    int flat = p * 1024 + threadIdx.x * 4;
    int d = flat >> 6, k = flat & 63;
    ushort4 o;
    o.x = f2bf(t[d][k + 0]); o.y = f2bf(t[d][k + 1]);
    o.z = f2bf(t[d][k + 2]); o.w = f2bf(t[d][k + 3]);
    *(ushort4*)(dst + (size_t)d * S_ + k) = o;
  }
}

__global__ __launch_bounds__(256) void smm_kernel(const float* __restrict__ x1,
                                                  const uint16_t* __restrict__ x2t,
                                                  float* __restrict__ out) {
  // grid: H * (S/QT) = 16*32 = 512 blocks (2 per CU)
  __shared__ __attribute__((aligned(16))) uint16_t pT[QT][KT];  // probs (bf16), swizzled
  __shared__ __attribute__((aligned(16))) uint16_t vT[D_][KT];  // V^T   (bf16), swizzled

  const int tid  = threadIdx.x;
  const int lane = tid & 63;
  const int w    = tid >> 6;          // wave 0..3 -> rows [16w,16w+16)
  const int h    = blockIdx.x >> 5;
  const int q0   = (blockIdx.x & 31) * QT;

  f32x4 acc[4];                        // D[16 x 64] per wave, 4 col-tiles
  f32x4 accS;                          // ones-column tile -> row sums in col 0
#pragma unroll
  for (int c = 0; c < 4; ++c) acc[c] = (f32x4){0.f, 0.f, 0.f, 0.f};
  accS = (f32x4){0.f, 0.f, 0.f, 0.f};

  // constant B fragment: B1[k][col] = (col == 0) ? 1 : 0
  bf16x8 ones;
  {
    short v = ((lane & 15) == 0) ? (short)0x3F80 : (short)0;
#pragma unroll
    for (int e = 0; e < 8; ++e) ones[e] = v;
  }

  const float* x1p = x1 + ((size_t)h * S_ + q0) * S_;
  const int prow = tid >> 5;           // 0..7  (x1 staging row base)
  const int pk4  = (tid & 31) << 2;    // 0..124 (float4 column)
  const int arow = lane & 15;          // row/col within 16-tile
  const int kgrp = lane >> 4;          // 0..3 (8-k group)

  for (int kt = 0; kt < NT; ++kt) {
    __syncthreads();  // WAR: previous iter's fragment reads done before overwrite

    // ---- stage probs: NT x1 load (no L2 allocate), exp, bf16, swizzled write ----
#pragma unroll
    for (int p = 0; p < 8; ++p) {
      int r = prow + p * 8;
      f32x4 v = __builtin_nontemporal_load(
          (const f32x4*)(x1p + (size_t)r * S_ + kt * KT + pk4));
      uint32_t lo = (uint32_t)f2bf(__expf(v[0])) | ((uint32_t)f2bf(__expf(v[1])) << 16);
      uint32_t hi = (uint32_t)f2bf(__expf(v[2])) | ((uint32_t)f2bf(__expf(v[3])) << 16);
      int byteoff = (pk4 * 2) ^ ((r & 15) << 4);   // XOR swizzle (16B slots)
      *(uint2*)((char*)(&pT[r][0]) + byteoff) = make_uint2(lo, hi);
    }

    // ---- stage V^T tile [64 d][128 k] bf16 (regular loads: want L2 hits) ----
    {
      const uint16_t* vp = x2t + (size_t)h * D_ * S_ + kt * KT;
#pragma unroll
      for (int p = 0; p < 4; ++p) {
        int flat = p * 256 + tid;
        int dd = flat >> 4;            // 0..63
        int ch = flat & 15;            // 16B chunk (8 bf16)
        uint4 v = *(const uint4*)(vp + (size_t)dd * S_ + ch * 8);
        int byteoff = (ch * 16) ^ ((dd & 15) << 4);
        *(uint4*)((char*)(&vT[dd][0]) + byteoff) = v;
      }
    }
    __syncthreads();

    // ---- MFMA: A = pT rows [16w..16w+16), B = vT cols, K = 128 (4 steps) ----
#pragma unroll
    for (int ks = 0; ks < 4; ++ks) {
      int kb = ks * 64 + kgrp * 16;    // byte offset within LDS row
      int ar = w * 16 + arow;
      bf16x8 a = *(const bf16x8*)((const char*)(&pT[ar][0]) + (kb ^ (arow << 4)));
      accS = __builtin_amdgcn_mfma_f32_16x16x32_bf16(a, ones, accS, 0, 0, 0);
#pragma unroll
      for (int c = 0; c < 4; ++c) {
        int bc = c * 16 + arow;
        bf16x8 b = *(const bf16x8*)((const char*)(&vT[bc][0]) + (kb ^ (arow << 4)));
        acc[c] = __builtin_amdgcn_mfma_f32_16x16x32_bf16(a, b, acc[c], 0, 0, 0);
      }
    }
  }

  // ---- epilogue: normalize by row sum, NT store fp32 ----
  // D layout: col = lane&15, row = (lane>>4)*4 + reg  [refcheck-verified R1]
  float* op = out + ((size_t)h * S_ + q0 + w * 16) * D_;
#pragma unroll
  for (int j = 0; j < 4; ++j) {
    float s = __shfl(accS[j], lane & 48);  // col-0 holder of this 16-lane group
    float rs = 1.0f / s;
    int row = (lane >> 4) * 4 + j;
#pragma unroll
    for (int c = 0; c < 4; ++c) {
      float o = acc[c][j] * rs;
      __builtin_nontemporal_store(o, op + (size_t)row * D_ + c * 16 + (lane & 15));
    }
  }
}

// ---------------- fallback (tiny workspace): R1 LDS kernel, no x2t ----------------
__global__ __launch_bounds__(256) void smm_lds(const float* __restrict__ x1,
                                               const float* __restrict__ x2,
                                               float* __restrict__ out) {
  __shared__ __attribute__((aligned(16))) uint16_t pT[QT][KT];
  __shared__ __attribute__((aligned(16))) uint16_t vT[D_][KT];

  const int tid  = threadIdx.x;
  const int lane = tid & 63;
  const int w    = tid >> 6;
  const int h    = blockIdx.x >> 5;
  const int q0   = (blockIdx.x & 31) * QT;

  f32x4 acc[4];
  f32x4 accS;
#pragma unroll
  for (int c = 0; c < 4; ++c) acc[c] = (f32x4){0.f, 0.f, 0.f, 0.f};
  accS = (f32x4){0.f, 0.f, 0.f, 0.f};

  bf16x8 ones;
  {
    short v = ((lane & 15) == 0) ? (short)0x3F80 : (short)0;
#pragma unroll
    for (int e = 0; e < 8; ++e) ones[e] = v;
  }

  const float* x1p = x1 + ((size_t)h * S_ + q0) * S_;
  const int prow = tid >> 5;
  const int pk4  = (tid & 31) << 2;
  const int arow = lane & 15;
  const int kgrp = lane >> 4;

  for (int kt = 0; kt < NT; ++kt) {
    __syncthreads();
#pragma unroll
    for (int p = 0; p < 8; ++p) {
      int r = prow + p * 8;
      float4 v = *(const float4*)(x1p + (size_t)r * S_ + kt * KT + pk4);
      uint32_t lo = (uint32_t)f2bf(__expf(v.x)) | ((uint32_t)f2bf(__expf(v.y)) << 16);
      uint32_t hi = (uint32_t)f2bf(__expf(v.z)) | ((uint32_t)f2bf(__expf(v.w)) << 16);
      int byteoff = (pk4 * 2) ^ ((r & 15) << 4);
      *(uint2*)((char*)(&pT[r][0]) + byteoff) = make_uint2(lo, hi);
    }
    {
      int dd = tid & 63;
      int kgq = tid >> 6;
      const float* src = x2 + ((size_t)h * S_ + kt * KT) * D_ + dd;
#pragma unroll
      for (int p = 0; p < 4; ++p) {
        int kb = p * 32 + kgq * 8;
        uint16_t tmp[8];
#pragma unroll
        for (int j = 0; j < 8; ++j) tmp[j] = f2bf(src[(size_t)(kb + j) * D_]);
        int byteoff = (kb * 2) ^ ((dd & 15) << 4);
        *(uint4*)((char*)(&vT[dd][0]) + byteoff) = *(uint4*)tmp;
      }
    }
    __syncthreads();
#pragma unroll
    for (int ks = 0; ks < 4; ++ks) {
      int kb = ks * 64 + kgrp * 16;
      int ar = w * 16 + arow;
      bf16x8 a = *(const bf16x8*)((const char*)(&pT[ar][0]) + (kb ^ (arow << 4)));
      accS = __builtin_amdgcn_mfma_f32_16x16x32_bf16(a, ones, accS, 0, 0, 0);
#pragma unroll
      for (int c = 0; c < 4; ++c) {
        int bc = c * 16 + arow;
        bf16x8 b = *(const bf16x8*)((const char*)(&vT[bc][0]) + (kb ^ (arow << 4)));
        acc[c] = __builtin_amdgcn_mfma_f32_16x16x32_bf16(a, b, acc[c], 0, 0, 0);
      }
    }
  }

  float* op = out + ((size_t)h * S_ + q0 + w * 16) * D_;
#pragma unroll
  for (int j = 0; j < 4; ++j) {
    float s = __shfl(accS[j], lane & 48);
    float rs = 1.0f / s;
    int row = (lane >> 4) * 4 + j;
#pragma unroll
    for (int c = 0; c < 4; ++c) {
      op[(size_t)row * D_ + c * 16 + (lane & 15)] = acc[c][j] * rs;
    }
  }
}

extern "C" void kernel_launch(void* const* d_in, const int* in_sizes, int n_in,
                              void* d_out, int out_size, void* d_ws, size_t ws_size,
                              hipStream_t stream) {
  const float* x1 = (const float*)d_in[0];
  const float* x2 = (const float*)d_in[1];
  float* out      = (float*)d_out;
  uint16_t* x2t   = (uint16_t*)d_ws;

  const size_t need = (size_t)H_ * D_ * S_ * sizeof(uint16_t);  // 4 MiB
  if (ws_size >= need) {
    vtrans_kernel<<<dim3(H_ * (S_ / 64)), dim3(256), 0, stream>>>(x2, x2t);
    smm_kernel<<<dim3(H_ * (S_ / QT)), dim3(256), 0, stream>>>(x1, x2t, out);
  } else {
    smm_lds<<<dim3(H_ * (S_ / QT)), dim3(256), 0, stream>>>(x1, x2, out);
  }
}

// Round 9
// 105.117 us; speedup vs baseline: 1.0927x; 1.0927x over previous
//
#include <hip/hip_runtime.h>
#include <hip/hip_bf16.h>
#include <stdint.h>

// out = softmax(x1, -1) @ x2
// x1: [1,16,2048,2048] fp32, x2: [1,16,2048,64] fp32, out: [1,16,2048,64] fp32
//
// R9 = R1 (64.4us, best) + ONE change: clustered bijective XCD swizzle so each
// XCD owns exactly 2 heads. Hot V slice per XCD = 512KB (stays in 4MiB L2;
// re-touched every ~4us by 32 blocks, while once-touched x1 lines evict first).
// R1's default dispatch spread every head across all XCDs -> concurrent V
// working set 4MB = whole L2, thrashed by the x1 stream -> ~128MB of V
// re-fetches from HBM. This removes them with zero structural change.
// LESSON (R4/R8): __builtin_nontemporal_load is ~2x slower for streams on
// gfx950 - no NT anywhere.

#define H_  16
#define S_  2048
#define D_  64
#define KT  128   // K elements staged per iteration
#define QT  64    // output rows per block (16 per wave, 4 waves)
#define NT  (S_ / KT)  // 16

typedef short bf16x8 __attribute__((ext_vector_type(8)));  // 8 bf16 (4 VGPRs)
typedef float f32x4  __attribute__((ext_vector_type(4)));

__device__ __forceinline__ uint16_t f2bf(float f) {  // round-to-nearest-even
  uint32_t u = __builtin_bit_cast(uint32_t, f);
  u += 0x7fffu + ((u >> 16) & 1u);
  return (uint16_t)(u >> 16);
}

// Pre-kernel: x2 [H][S][D] fp32  ->  x2t [H][D][S] bf16 (k-contiguous rows)
__global__ __launch_bounds__(256) void vtrans_kernel(const float* __restrict__ x2,
                                                     uint16_t* __restrict__ x2t) {
  __shared__ float t[D_][64 + 1];  // +1 pad: bank-conflict-free transpose
  const int h  = blockIdx.x >> 5;
  const int k0 = (blockIdx.x & 31) << 6;  // 64-k tile
  const float* src = x2 + ((size_t)h * S_ + k0) * D_;
#pragma unroll
  for (int p = 0; p < 4; ++p) {
    int flat = p * 1024 + threadIdx.x * 4;
    int k = flat >> 6, d = flat & 63;
    float4 v = *(const float4*)(src + (size_t)k * D_ + d);
    t[d + 0][k] = v.x; t[d + 1][k] = v.y; t[d + 2][k] = v.z; t[d + 3][k] = v.w;
  }
  __syncthreads();
  uint16_t* dst = x2t + (size_t)h * D_ * S_ + k0;
#pragma unroll
  for (int p = 0; p < 4; ++p) {
    int flat = p * 1024 + threadIdx.x * 4;
    int d = flat >> 6, k = flat & 63;
    ushort4 o;
    o.x = f2bf(t[d][k + 0]); o.y = f2bf(t[d][k + 1]);
    o.z = f2bf(t[d][k + 2]); o.w = f2bf(t[d][k + 3]);
    *(ushort4*)(dst + (size_t)d * S_ + k) = o;
  }
}

__global__ __launch_bounds__(256) void smm_kernel(const float* __restrict__ x1,
                                                  const uint16_t* __restrict__ x2t,
                                                  float* __restrict__ out) {
  // grid: 512 blocks; clustered bijective XCD swizzle: XCD i -> bids
  // [i*64,(i+1)*64) = heads 2i,2i+1 (512 = 8 XCDs x 64, exact).
  __shared__ __attribute__((aligned(16))) uint16_t pT[QT][KT];  // probs (bf16), swizzled
  __shared__ __attribute__((aligned(16))) uint16_t vT[D_][KT];  // V^T   (bf16), swizzled

  const int bid  = ((int)blockIdx.x & 7) * 64 + ((int)blockIdx.x >> 3);
  const int tid  = threadIdx.x;
  const int lane = tid & 63;
  const int w    = tid >> 6;          // wave 0..3 -> rows [16w,16w+16)
  const int h    = bid >> 5;
  const int q0   = (bid & 31) * QT;

  f32x4 acc[4];                        // D[16 x 64] per wave, 4 col-tiles
  f32x4 accS;                          // ones-column tile -> row sums in col 0
#pragma unroll
  for (int c = 0; c < 4; ++c) acc[c] = (f32x4){0.f, 0.f, 0.f, 0.f};
  accS = (f32x4){0.f, 0.f, 0.f, 0.f};

  // constant B fragment: B1[k][col] = (col == 0) ? 1 : 0
  bf16x8 ones;
  {
    short v = ((lane & 15) == 0) ? (short)0x3F80 : (short)0;
#pragma unroll
    for (int e = 0; e < 8; ++e) ones[e] = v;
  }

  const float* x1p = x1 + ((size_t)h * S_ + q0) * S_;
  const int prow = tid >> 5;           // 0..7  (x1 staging row base)
  const int pk4  = (tid & 31) << 2;    // 0..124 (float4 column)
  const int arow = lane & 15;          // row/col within 16-tile
  const int kgrp = lane >> 4;          // 0..3 (8-k group)

  for (int kt = 0; kt < NT; ++kt) {
    __syncthreads();  // WAR: previous iter's fragment reads done before overwrite

    // ---- stage probs: load x1 coalesced, exp, bf16, swizzled LDS write ----
#pragma unroll
    for (int p = 0; p < 8; ++p) {
      int r = prow + p * 8;
      float4 v = *(const float4*)(x1p + (size_t)r * S_ + kt * KT + pk4);
      uint32_t lo = (uint32_t)f2bf(__expf(v.x)) | ((uint32_t)f2bf(__expf(v.y)) << 16);
      uint32_t hi = (uint32_t)f2bf(__expf(v.z)) | ((uint32_t)f2bf(__expf(v.w)) << 16);
      int byteoff = (pk4 * 2) ^ ((r & 15) << 4);   // XOR swizzle (16B slots)
      *(uint2*)((char*)(&pT[r][0]) + byteoff) = make_uint2(lo, hi);
    }

    // ---- stage V^T tile [64 d][128 k] bf16 ----
    {
      const uint16_t* vp = x2t + (size_t)h * D_ * S_ + kt * KT;
#pragma unroll
      for (int p = 0; p < 4; ++p) {
        int flat = p * 256 + tid;
        int dd = flat >> 4;            // 0..63
        int ch = flat & 15;            // 16B chunk (8 bf16)
        uint4 v = *(const uint4*)(vp + (size_t)dd * S_ + ch * 8);
        int byteoff = (ch * 16) ^ ((dd & 15) << 4);
        *(uint4*)((char*)(&vT[dd][0]) + byteoff) = v;
      }
    }
    __syncthreads();

    // ---- MFMA: A = pT rows [16w..16w+16), B = vT cols, K = 128 (4 steps) ----
#pragma unroll
    for (int ks = 0; ks < 4; ++ks) {
      int kb = ks * 64 + kgrp * 16;    // byte offset within LDS row
      int ar = w * 16 + arow;
      bf16x8 a = *(const bf16x8*)((const char*)(&pT[ar][0]) + (kb ^ (arow << 4)));
      accS = __builtin_amdgcn_mfma_f32_16x16x32_bf16(a, ones, accS, 0, 0, 0);
#pragma unroll
      for (int c = 0; c < 4; ++c) {
        int bc = c * 16 + arow;
        bf16x8 b = *(const bf16x8*)((const char*)(&vT[bc][0]) + (kb ^ (arow << 4)));
        acc[c] = __builtin_amdgcn_mfma_f32_16x16x32_bf16(a, b, acc[c], 0, 0, 0);
      }
    }
  }

  // ---- epilogue: normalize by row sum, store fp32 ----
  // D layout: col = lane&15, row = (lane>>4)*4 + reg  [refcheck-verified R1]
  float* op = out + ((size_t)h * S_ + q0 + w * 16) * D_;
#pragma unroll
  for (int j = 0; j < 4; ++j) {
    float s = __shfl(accS[j], lane & 48);  // col-0 holder of this 16-lane group
    float rs = 1.0f / s;
    int row = (lane >> 4) * 4 + j;
#pragma unroll
    for (int c = 0; c < 4; ++c) {
      op[(size_t)row * D_ + c * 16 + (lane & 15)] = acc[c][j] * rs;
    }
  }
}

// ---------------- fallback (tiny workspace): R1 LDS kernel, no x2t ----------------
__global__ __launch_bounds__(256) void smm_lds(const float* __restrict__ x1,
                                               const float* __restrict__ x2,
                                               float* __restrict__ out) {
  __shared__ __attribute__((aligned(16))) uint16_t pT[QT][KT];
  __shared__ __attribute__((aligned(16))) uint16_t vT[D_][KT];

  const int tid  = threadIdx.x;
  const int lane = tid & 63;
  const int w    = tid >> 6;
  const int h    = blockIdx.x >> 5;
  const int q0   = (blockIdx.x & 31) * QT;

  f32x4 acc[4];
  f32x4 accS;
#pragma unroll
  for (int c = 0; c < 4; ++c) acc[c] = (f32x4){0.f, 0.f, 0.f, 0.f};
  accS = (f32x4){0.f, 0.f, 0.f, 0.f};

  bf16x8 ones;
  {
    short v = ((lane & 15) == 0) ? (short)0x3F80 : (short)0;
#pragma unroll
    for (int e = 0; e < 8; ++e) ones[e] = v;
  }

  const float* x1p = x1 + ((size_t)h * S_ + q0) * S_;
  const int prow = tid >> 5;
  const int pk4  = (tid & 31) << 2;
  const int arow = lane & 15;
  const int kgrp = lane >> 4;

  for (int kt = 0; kt < NT; ++kt) {
    __syncthreads();
#pragma unroll
    for (int p = 0; p < 8; ++p) {
      int r = prow + p * 8;
      float4 v = *(const float4*)(x1p + (size_t)r * S_ + kt * KT + pk4);
      uint32_t lo = (uint32_t)f2bf(__expf(v.x)) | ((uint32_t)f2bf(__expf(v.y)) << 16);
      uint32_t hi = (uint32_t)f2bf(__expf(v.z)) | ((uint32_t)f2bf(__expf(v.w)) << 16);
      int byteoff = (pk4 * 2) ^ ((r & 15) << 4);
      *(uint2*)((char*)(&pT[r][0]) + byteoff) = make_uint2(lo, hi);
    }
    {
      int dd = tid & 63;
      int kgq = tid >> 6;
      const float* src = x2 + ((size_t)h * S_ + kt * KT) * D_ + dd;
#pragma unroll
      for (int p = 0; p < 4; ++p) {
        int kb = p * 32 + kgq * 8;
        uint16_t tmp[8];
#pragma unroll
        for (int j = 0; j < 8; ++j) tmp[j] = f2bf(src[(size_t)(kb + j) * D_]);
        int byteoff = (kb * 2) ^ ((dd & 15) << 4);
        *(uint4*)((char*)(&vT[dd][0]) + byteoff) = *(uint4*)tmp;
      }
    }
    __syncthreads();
#pragma unroll
    for (int ks = 0; ks < 4; ++ks) {
      int kb = ks * 64 + kgrp * 16;
      int ar = w * 16 + arow;
      bf16x8 a = *(const bf16x8*)((const char*)(&pT[ar][0]) + (kb ^ (arow << 4)));
      accS = __builtin_amdgcn_mfma_f32_16x16x32_bf16(a, ones, accS, 0, 0, 0);
#pragma unroll
      for (int c = 0; c < 4; ++c) {
        int bc = c * 16 + arow;
        bf16x8 b = *(const bf16x8*)((const char*)(&vT[bc][0]) + (kb ^ (arow << 4)));
        acc[c] = __builtin_amdgcn_mfma_f32_16x16x32_bf16(a, b, acc[c], 0, 0, 0);
      }
    }
  }

  float* op = out + ((size_t)h * S_ + q0 + w * 16) * D_;
#pragma unroll
  for (int j = 0; j < 4; ++j) {
    float s = __shfl(accS[j], lane & 48);
    float rs = 1.0f / s;
    int row = (lane >> 4) * 4 + j;
#pragma unroll
    for (int c = 0; c < 4; ++c) {
      op[(size_t)row * D_ + c * 16 + (lane & 15)] = acc[c][j] * rs;
    }
  }
}

extern "C" void kernel_launch(void* const* d_in, const int* in_sizes, int n_in,
                              void* d_out, int out_size, void* d_ws, size_t ws_size,
                              hipStream_t stream) {
  const float* x1 = (const float*)d_in[0];
  const float* x2 = (const float*)d_in[1];
  float* out      = (float*)d_out;
  uint16_t* x2t   = (uint16_t*)d_ws;

  const size_t need = (size_t)H_ * D_ * S_ * sizeof(uint16_t);  // 4 MiB
  if (ws_size >= need) {
    vtrans_kernel<<<dim3(H_ * (S_ / 64)), dim3(256), 0, stream>>>(x2, x2t);
    smm_kernel<<<dim3(H_ * (S_ / QT)), dim3(256), 0, stream>>>(x1, x2t, out);
  } else {
    smm_lds<<<dim3(H_ * (S_ / QT)), dim3(256), 0, stream>>>(x1, x2, out);
  }
}